// Round 9
// baseline (59.599 us; speedup 1.0000x reference)
//
#include <hip/hip_runtime.h>
#include <hip/hip_bf16.h>

#define D 64  // D_IN == D_OUT == 64

typedef __attribute__((ext_vector_type(8))) short bf16x8;
typedef __attribute__((ext_vector_type(4))) float f32x4;

static __device__ __forceinline__ ushort f2bf(float x) {
  __hip_bfloat16 h = __float2bfloat16(x);  // RNE
  return *reinterpret_cast<ushort*>(&h);
}

// ---------------------------------------------------------------------------
// Kernel 1: dense h = feat@W + b via bf16 MFMA, a1/a2 epilogue.
//   Blocks [0, n_tiles): one 64-node tile (4 waves, wave w = rows w*16..).
//   Blocks [n_tiles, ...): fused row_start (CSR pointer) build.
//   (unchanged from round 6)
// ---------------------------------------------------------------------------
__global__ __launch_bounds__(256) void node_kernel(
    const float* __restrict__ feat, const float* __restrict__ W,
    const float* __restrict__ b, const float* __restrict__ w1,
    const float* __restrict__ b1s, const float* __restrict__ w2,
    const float* __restrict__ b2s,
    ushort* __restrict__ hb, float* __restrict__ a1, float* __restrict__ a2,
    int n_nodes,
    const int* __restrict__ rows, int* __restrict__ startp, int n_edges,
    int n_tiles) {
  const int tid = threadIdx.x;

  if (blockIdx.x >= n_tiles) {  // ---------------- row_start blocks
    const int i = (blockIdx.x - n_tiles) * 256 + tid;
    if (i < n_edges) {
      const int r  = rows[i];
      const int rp = (i == 0) ? -1 : rows[i - 1];
      for (int m = rp + 1; m <= r; ++m) startp[m] = i;
      if (i == n_edges - 1) {
        for (int m = r + 1; m <= n_nodes; ++m) startp[m] = n_edges;
      }
    }
    return;
  }

  // ---------------- node (MFMA) blocks ----------------
  __shared__ ushort BT_lds[64 * 64];  // W^T bf16: BT[n][k] = W[k][n]
  const int lane = tid & 63;
  const int wave = tid >> 6;
  const int c16  = lane & 15;
  const int g16  = lane >> 4;

  {
    const int k  = tid >> 2;
    const int n0 = (tid & 3) * 16;
    const float4* wrow = (const float4*)(W + k * 64 + n0);
    #pragma unroll
    for (int q = 0; q < 4; ++q) {
      float4 v = wrow[q];
      BT_lds[(n0 + 4 * q + 0) * 64 + k] = f2bf(v.x);
      BT_lds[(n0 + 4 * q + 1) * 64 + k] = f2bf(v.y);
      BT_lds[(n0 + 4 * q + 2) * 64 + k] = f2bf(v.z);
      BT_lds[(n0 + 4 * q + 3) * 64 + k] = f2bf(v.w);
    }
  }

  float bc[4], w1c[4], w2c[4];
  #pragma unroll
  for (int t = 0; t < 4; ++t) {
    bc[t]  = b[t * 16 + c16];
    w1c[t] = w1[t * 16 + c16];
    w2c[t] = w2[t * 16 + c16];
  }
  const float b1v = b1s[0];
  const float b2v = b2s[0];

  const int nbase = blockIdx.x * 64;
  const int arow_raw = nbase + wave * 16 + c16;
  const int arow = (arow_raw < n_nodes) ? arow_raw : (n_nodes - 1);
  const float* fr = feat + (size_t)arow * D;
  const float4* fa = (const float4*)(fr + g16 * 8);
  const float4* fb = (const float4*)(fr + 32 + g16 * 8);
  const float4 a00 = fa[0], a01 = fa[1];
  const float4 a10 = fb[0], a11 = fb[1];
  bf16x8 af0, af1;
  af0[0]=f2bf(a00.x); af0[1]=f2bf(a00.y); af0[2]=f2bf(a00.z); af0[3]=f2bf(a00.w);
  af0[4]=f2bf(a01.x); af0[5]=f2bf(a01.y); af0[6]=f2bf(a01.z); af0[7]=f2bf(a01.w);
  af1[0]=f2bf(a10.x); af1[1]=f2bf(a10.y); af1[2]=f2bf(a10.z); af1[3]=f2bf(a10.w);
  af1[4]=f2bf(a11.x); af1[5]=f2bf(a11.y); af1[6]=f2bf(a11.z); af1[7]=f2bf(a11.w);

  __syncthreads();

  bf16x8 bfrag[4][2];
  #pragma unroll
  for (int t = 0; t < 4; ++t)
    #pragma unroll
    for (int s = 0; s < 2; ++s)
      bfrag[t][s] = *(const bf16x8*)(BT_lds + (t * 16 + c16) * 64 + s * 32 + g16 * 8);

  f32x4 acc[4];
  #pragma unroll
  for (int t = 0; t < 4; ++t) acc[t] = (f32x4){0.f, 0.f, 0.f, 0.f};
  #pragma unroll
  for (int t = 0; t < 4; ++t) {
    acc[t] = __builtin_amdgcn_mfma_f32_16x16x32_bf16(af0, bfrag[t][0], acc[t], 0, 0, 0);
    acc[t] = __builtin_amdgcn_mfma_f32_16x16x32_bf16(af1, bfrag[t][1], acc[t], 0, 0, 0);
  }

  #pragma unroll
  for (int r = 0; r < 4; ++r) {
    const int nrow = nbase + wave * 16 + g16 * 4 + r;
    const bool ok = nrow < n_nodes;
    const float hv0 = acc[0][r] + bc[0];
    const float hv1 = acc[1][r] + bc[1];
    const float hv2 = acc[2][r] + bc[2];
    const float hv3 = acc[3][r] + bc[3];
    if (ok) {
      ushort* hrow = hb + (size_t)nrow * D;
      hrow[ 0 + c16] = f2bf(hv0);
      hrow[16 + c16] = f2bf(hv1);
      hrow[32 + c16] = f2bf(hv2);
      hrow[48 + c16] = f2bf(hv3);
    }
    float p1 = hv0 * w1c[0] + hv1 * w1c[1] + hv2 * w1c[2] + hv3 * w1c[3];
    float p2 = hv0 * w2c[0] + hv1 * w2c[1] + hv2 * w2c[2] + hv3 * w2c[3];
    #pragma unroll
    for (int off = 8; off > 0; off >>= 1) {
      p1 += __shfl_xor(p1, off);
      p2 += __shfl_xor(p2, off);
    }
    if (ok && c16 == 0) { a1[nrow] = p1 + b1v; a2[nrow] = p2 + b2v; }
  }
}

// ---------------------------------------------------------------------------
// Kernel 2: per-edge ex precompute.  exf[i] = exp(a1[rows[i]] + a2[cols[i]]).
//   Streaming: rows/cols coalesced; a1 gather is on SORTED rows (sequential,
//   L1-friendly); a2 gather is random 4B within 400 KB (L2-resident).
//   Removes the dependent gather+exp chain from the hot edge kernel.
// ---------------------------------------------------------------------------
__global__ __launch_bounds__(256) void pack_kernel(
    const int* __restrict__ rows, const int* __restrict__ cols,
    const float* __restrict__ a1, const float* __restrict__ a2,
    float* __restrict__ exf, int n_edges) {
  const int i = blockIdx.x * 256 + threadIdx.x;
  if (i >= n_edges) return;
  const float ex = __expf(a1[rows[i]] + a2[cols[i]]);
  __builtin_nontemporal_store(ex, exf + i);
}

// ---------------------------------------------------------------------------
// Kernel 3 v7: sparse softmax + aggregation (r6 structure, exf header).
//   8 rows/wave, 8 lanes/row, lane owns 8 bf16 cols (uint4 gather).
//   Per 8-edge chunk: TWO independent coalesced header loads (cols, exf) —
//   no dependent a2 gather, no exp. Shuffle-broadcast, 8 independent h-row
//   gathers. Next chunk's header issued before consuming current gathers.
// ---------------------------------------------------------------------------
__global__ __launch_bounds__(256) void edge_kernel(
    const int* __restrict__ cols, const float* __restrict__ exf,
    const int* __restrict__ start, const ushort* __restrict__ hb,
    float* __restrict__ out, int n_nodes) {
  const int lane = threadIdx.x & 63;
  const int wave = threadIdx.x >> 6;
  const int g = lane >> 3;                  // group = row slot (0..7)
  const int l = lane & 7;                   // lane within group
  const int row = (blockIdx.x * 4 + wave) * 8 + g;
  const bool valid = row < n_nodes;

  int s = 0, e = 0;
  if (valid) {
    s = start[row];
    e = start[row + 1];
  }

  float acc0=0.f, acc1=0.f, acc2=0.f, acc3=0.f;
  float acc4=0.f, acc5=0.f, acc6=0.f, acc7=0.f;
  float denom = 0.f;

  // prefetch chunk-0 header (two independent coalesced loads)
  int colv = 0;
  float ex = 0.f;
  {
    const int i = s + l;
    if (i < e) {
      colv = __builtin_nontemporal_load(cols + i);
      ex   = __builtin_nontemporal_load(exf + i);
    }
  }

  for (int base = s; base < e; base += 8) {
    // issue next chunk's header loads early
    int coln = 0;
    float exn = 0.f;
    {
      const int i = base + 8 + l;
      if (i < e) {
        coln = __builtin_nontemporal_load(cols + i);
        exn  = __builtin_nontemporal_load(exf + i);
      }
    }

    #pragma unroll
    for (int j = 0; j < 8; ++j) {
      const int src = (g << 3) + j;
      const float exj = __shfl(ex, src);
      const int colj  = __shfl(colv, src);
      const uint4 hv = ((const uint4*)(hb + ((size_t)colj << 6)))[l];
      acc0 = fmaf(exj, __uint_as_float(hv.x << 16),         acc0);
      acc1 = fmaf(exj, __uint_as_float(hv.x & 0xffff0000u), acc1);
      acc2 = fmaf(exj, __uint_as_float(hv.y << 16),         acc2);
      acc3 = fmaf(exj, __uint_as_float(hv.y & 0xffff0000u), acc3);
      acc4 = fmaf(exj, __uint_as_float(hv.z << 16),         acc4);
      acc5 = fmaf(exj, __uint_as_float(hv.z & 0xffff0000u), acc5);
      acc6 = fmaf(exj, __uint_as_float(hv.w << 16),         acc6);
      acc7 = fmaf(exj, __uint_as_float(hv.w & 0xffff0000u), acc7);
      denom += exj;                          // uniform within group
    }

    colv = coln;
    ex = exn;
  }

  if (valid) {
    const float sc = (denom > 0.f) ? (1.f / denom) : 0.f;
    float* op = out + (size_t)row * D + l * 8;
    f32x4 o0 = {acc0 * sc, acc1 * sc, acc2 * sc, acc3 * sc};
    f32x4 o1 = {acc4 * sc, acc5 * sc, acc6 * sc, acc7 * sc};
    __builtin_nontemporal_store(o0, (f32x4*)op);
    __builtin_nontemporal_store(o1, (f32x4*)(op + 4));
  }
}

// ---------------------------------------------------------------------------
extern "C" void kernel_launch(void* const* d_in, const int* in_sizes, int n_in,
                              void* d_out, int out_size, void* d_ws, size_t ws_size,
                              hipStream_t stream) {
  const float* feat = (const float*)d_in[0];
  const int*   rows = (const int*)d_in[1];
  const int*   cols = (const int*)d_in[2];
  const float* W    = (const float*)d_in[3];
  const float* b    = (const float*)d_in[4];
  const float* w1   = (const float*)d_in[5];
  const float* b1   = (const float*)d_in[6];
  const float* w2   = (const float*)d_in[7];
  const float* b2   = (const float*)d_in[8];

  const int n_nodes = in_sizes[0] / D;
  const int n_edges = in_sizes[1];
  float* out = (float*)d_out;

  // Workspace: exf f32 [E] | hb bf16 [N*64] | a1 f32 [N] | a2 f32 [N] | start i32 [N+1]
  char* ws = (char*)d_ws;
  float* exf = (float*)ws;
  ushort* hbuf = (ushort*)(ws + (size_t)n_edges * sizeof(float));
  float* a1 = (float*)((char*)hbuf + (size_t)n_nodes * D * sizeof(ushort));
  float* a2 = a1 + n_nodes;
  int* start = (int*)(a2 + n_nodes);

  const int n_tiles   = (n_nodes + 63) >> 6;
  const int rs_blocks = (n_edges + 255) >> 8;
  node_kernel<<<n_tiles + rs_blocks, 256, 0, stream>>>(
      feat, W, b, w1, b1, w2, b2, hbuf, a1, a2, n_nodes,
      rows, start, n_edges, n_tiles);

  pack_kernel<<<(n_edges + 255) / 256, 256, 0, stream>>>(
      rows, cols, a1, a2, exf, n_edges);

  const int rows_per_block = 32;  // 4 waves x 8 rows
  edge_kernel<<<(n_nodes + rows_per_block - 1) / rows_per_block, 256, 0, stream>>>(
      cols, exf, start, hbuf, out, n_nodes);
}

// Round 10
// 51.559 us; speedup vs baseline: 1.1559x; 1.1559x over previous
//
#include <hip/hip_runtime.h>
#include <hip/hip_bf16.h>

#define D 64  // D_IN == D_OUT == 64

typedef __attribute__((ext_vector_type(8))) short bf16x8;
typedef __attribute__((ext_vector_type(4))) float f32x4;

static __device__ __forceinline__ ushort f2bf(float x) {
  __hip_bfloat16 h = __float2bfloat16(x);  // RNE
  return *reinterpret_cast<ushort*>(&h);
}

// ---------------------------------------------------------------------------
// Kernel 1: dense h = feat@W + b via bf16 MFMA, a1/a2 epilogue.
//   Blocks [0, n_tiles): one 64-node tile (4 waves, wave w = rows w*16..).
//   Blocks [n_tiles, ...): fused row_start (CSR pointer) build.
// ---------------------------------------------------------------------------
__global__ __launch_bounds__(256) void node_kernel(
    const float* __restrict__ feat, const float* __restrict__ W,
    const float* __restrict__ b, const float* __restrict__ w1,
    const float* __restrict__ b1s, const float* __restrict__ w2,
    const float* __restrict__ b2s,
    ushort* __restrict__ hb, float* __restrict__ a1, float* __restrict__ a2,
    int n_nodes,
    const int* __restrict__ rows, int* __restrict__ startp, int n_edges,
    int n_tiles) {
  const int tid = threadIdx.x;

  if (blockIdx.x >= n_tiles) {  // ---------------- row_start blocks
    const int i = (blockIdx.x - n_tiles) * 256 + tid;
    if (i < n_edges) {
      const int r  = rows[i];
      const int rp = (i == 0) ? -1 : rows[i - 1];
      for (int m = rp + 1; m <= r; ++m) startp[m] = i;
      if (i == n_edges - 1) {
        for (int m = r + 1; m <= n_nodes; ++m) startp[m] = n_edges;
      }
    }
    return;
  }

  // ---------------- node (MFMA) blocks ----------------
  __shared__ ushort BT_lds[64 * 64];  // W^T bf16: BT[n][k] = W[k][n]
  const int lane = tid & 63;
  const int wave = tid >> 6;
  const int c16  = lane & 15;
  const int g16  = lane >> 4;

  {
    const int k  = tid >> 2;
    const int n0 = (tid & 3) * 16;
    const float4* wrow = (const float4*)(W + k * 64 + n0);
    #pragma unroll
    for (int q = 0; q < 4; ++q) {
      float4 v = wrow[q];
      BT_lds[(n0 + 4 * q + 0) * 64 + k] = f2bf(v.x);
      BT_lds[(n0 + 4 * q + 1) * 64 + k] = f2bf(v.y);
      BT_lds[(n0 + 4 * q + 2) * 64 + k] = f2bf(v.z);
      BT_lds[(n0 + 4 * q + 3) * 64 + k] = f2bf(v.w);
    }
  }

  float bc[4], w1c[4], w2c[4];
  #pragma unroll
  for (int t = 0; t < 4; ++t) {
    bc[t]  = b[t * 16 + c16];
    w1c[t] = w1[t * 16 + c16];
    w2c[t] = w2[t * 16 + c16];
  }
  const float b1v = b1s[0];
  const float b2v = b2s[0];

  const int nbase = blockIdx.x * 64;
  const int arow_raw = nbase + wave * 16 + c16;
  const int arow = (arow_raw < n_nodes) ? arow_raw : (n_nodes - 1);
  const float* fr = feat + (size_t)arow * D;
  const float4* fa = (const float4*)(fr + g16 * 8);
  const float4* fb = (const float4*)(fr + 32 + g16 * 8);
  const float4 a00 = fa[0], a01 = fa[1];
  const float4 a10 = fb[0], a11 = fb[1];
  bf16x8 af0, af1;
  af0[0]=f2bf(a00.x); af0[1]=f2bf(a00.y); af0[2]=f2bf(a00.z); af0[3]=f2bf(a00.w);
  af0[4]=f2bf(a01.x); af0[5]=f2bf(a01.y); af0[6]=f2bf(a01.z); af0[7]=f2bf(a01.w);
  af1[0]=f2bf(a10.x); af1[1]=f2bf(a10.y); af1[2]=f2bf(a10.z); af1[3]=f2bf(a10.w);
  af1[4]=f2bf(a11.x); af1[5]=f2bf(a11.y); af1[6]=f2bf(a11.z); af1[7]=f2bf(a11.w);

  __syncthreads();

  bf16x8 bfrag[4][2];
  #pragma unroll
  for (int t = 0; t < 4; ++t)
    #pragma unroll
    for (int s = 0; s < 2; ++s)
      bfrag[t][s] = *(const bf16x8*)(BT_lds + (t * 16 + c16) * 64 + s * 32 + g16 * 8);

  f32x4 acc[4];
  #pragma unroll
  for (int t = 0; t < 4; ++t) acc[t] = (f32x4){0.f, 0.f, 0.f, 0.f};
  #pragma unroll
  for (int t = 0; t < 4; ++t) {
    acc[t] = __builtin_amdgcn_mfma_f32_16x16x32_bf16(af0, bfrag[t][0], acc[t], 0, 0, 0);
    acc[t] = __builtin_amdgcn_mfma_f32_16x16x32_bf16(af1, bfrag[t][1], acc[t], 0, 0, 0);
  }

  #pragma unroll
  for (int r = 0; r < 4; ++r) {
    const int nrow = nbase + wave * 16 + g16 * 4 + r;
    const bool ok = nrow < n_nodes;
    const float hv0 = acc[0][r] + bc[0];
    const float hv1 = acc[1][r] + bc[1];
    const float hv2 = acc[2][r] + bc[2];
    const float hv3 = acc[3][r] + bc[3];
    if (ok) {
      ushort* hrow = hb + (size_t)nrow * D;
      hrow[ 0 + c16] = f2bf(hv0);
      hrow[16 + c16] = f2bf(hv1);
      hrow[32 + c16] = f2bf(hv2);
      hrow[48 + c16] = f2bf(hv3);
    }
    float p1 = hv0 * w1c[0] + hv1 * w1c[1] + hv2 * w1c[2] + hv3 * w1c[3];
    float p2 = hv0 * w2c[0] + hv1 * w2c[1] + hv2 * w2c[2] + hv3 * w2c[3];
    #pragma unroll
    for (int off = 8; off > 0; off >>= 1) {
      p1 += __shfl_xor(p1, off);
      p2 += __shfl_xor(p2, off);
    }
    if (ok && c16 == 0) { a1[nrow] = p1 + b1v; a2[nrow] = p2 + b2v; }
  }
}

// ---------------------------------------------------------------------------
// Kernel 2 (r6 config): sparse softmax + aggregation.
//   8 rows/wave, 8 lanes/row, lane owns 8 bf16 cols (uint4 = 16 B gather).
//   Per 8-edge chunk: ONE coalesced cols load + ONE a2 gather per lane,
//   shuffle-broadcast (ex, col), 8 independent h-row gathers.
//   Next chunk's header loads issued before consuming current gathers.
// ---------------------------------------------------------------------------
__global__ __launch_bounds__(256) void edge_kernel(
    const int* __restrict__ cols, const int* __restrict__ start,
    const ushort* __restrict__ hb, const float* __restrict__ a1,
    const float* __restrict__ a2, float* __restrict__ out, int n_nodes) {
  const int lane = threadIdx.x & 63;
  const int wave = threadIdx.x >> 6;
  const int g = lane >> 3;                  // group = row slot (0..7)
  const int l = lane & 7;                   // lane within group
  const int row = (blockIdx.x * 4 + wave) * 8 + g;
  const bool valid = row < n_nodes;

  int s = 0, e = 0;
  float a1n = 0.f;
  if (valid) {
    s = start[row];
    e = start[row + 1];
    a1n = a1[row];
  }

  float acc0=0.f, acc1=0.f, acc2=0.f, acc3=0.f;
  float acc4=0.f, acc5=0.f, acc6=0.f, acc7=0.f;
  float denom = 0.f;

  // prefetch chunk 0 header
  int colv = 0;
  float a2v = 0.f;
  bool lv = (s + l) < e;
  if (lv) {
    colv = __builtin_nontemporal_load(cols + s + l);
    a2v  = a2[colv];
  }

  for (int base = s; base < e; base += 8) {
    // issue next chunk's header loads early (overlap with this chunk's gathers)
    int coln = 0;
    float a2n = 0.f;
    const int inext = base + 8 + l;
    const bool lvn = inext < e;
    if (lvn) {
      coln = __builtin_nontemporal_load(cols + inext);
      a2n  = a2[coln];
    }

    const float ex = lv ? __expf(a1n + a2v) : 0.f;

    #pragma unroll
    for (int j = 0; j < 8; ++j) {
      const int src = (g << 3) + j;
      const float exj = __shfl(ex, src);
      const int colj  = __shfl(colv, src);
      const uint4 hv = ((const uint4*)(hb + ((size_t)colj << 6)))[l];
      acc0 = fmaf(exj, __uint_as_float(hv.x << 16),         acc0);
      acc1 = fmaf(exj, __uint_as_float(hv.x & 0xffff0000u), acc1);
      acc2 = fmaf(exj, __uint_as_float(hv.y << 16),         acc2);
      acc3 = fmaf(exj, __uint_as_float(hv.y & 0xffff0000u), acc3);
      acc4 = fmaf(exj, __uint_as_float(hv.z << 16),         acc4);
      acc5 = fmaf(exj, __uint_as_float(hv.z & 0xffff0000u), acc5);
      acc6 = fmaf(exj, __uint_as_float(hv.w << 16),         acc6);
      acc7 = fmaf(exj, __uint_as_float(hv.w & 0xffff0000u), acc7);
      denom += exj;                          // uniform within group
    }

    colv = coln;
    a2v = a2n;
    lv = lvn;
  }

  if (valid) {
    const float sc = (denom > 0.f) ? (1.f / denom) : 0.f;
    float* op = out + (size_t)row * D + l * 8;
    f32x4 o0 = {acc0 * sc, acc1 * sc, acc2 * sc, acc3 * sc};
    f32x4 o1 = {acc4 * sc, acc5 * sc, acc6 * sc, acc7 * sc};
    __builtin_nontemporal_store(o0, (f32x4*)op);
    __builtin_nontemporal_store(o1, (f32x4*)(op + 4));
  }
}

// ---------------------------------------------------------------------------
extern "C" void kernel_launch(void* const* d_in, const int* in_sizes, int n_in,
                              void* d_out, int out_size, void* d_ws, size_t ws_size,
                              hipStream_t stream) {
  const float* feat = (const float*)d_in[0];
  const int*   rows = (const int*)d_in[1];
  const int*   cols = (const int*)d_in[2];
  const float* W    = (const float*)d_in[3];
  const float* b    = (const float*)d_in[4];
  const float* w1   = (const float*)d_in[5];
  const float* b1   = (const float*)d_in[6];
  const float* w2   = (const float*)d_in[7];
  const float* b2   = (const float*)d_in[8];

  const int n_nodes = in_sizes[0] / D;
  const int n_edges = in_sizes[1];
  float* out = (float*)d_out;

  // Workspace: hb bf16 [N*64] | a1 f32 [N] | a2 f32 [N] | row_start i32 [N+1]
  char* ws = (char*)d_ws;
  ushort* hbuf = (ushort*)ws;
  float* a1 = (float*)(ws + (size_t)n_nodes * D * sizeof(ushort));
  float* a2 = a1 + n_nodes;
  int* start = (int*)(a2 + n_nodes);

  const int n_tiles   = (n_nodes + 63) >> 6;
  const int rs_blocks = (n_edges + 255) >> 8;
  node_kernel<<<n_tiles + rs_blocks, 256, 0, stream>>>(
      feat, W, b, w1, b1, w2, b2, hbuf, a1, a2, n_nodes,
      rows, start, n_edges, n_tiles);

  const int rows_per_block = 32;  // 4 waves x 8 rows
  edge_kernel<<<(n_nodes + rows_per_block - 1) / rows_per_block, 256, 0, stream>>>(
      cols, start, hbuf, a1, a2, out, n_nodes);
}